// Round 5
// baseline (115.501 us; speedup 1.0000x reference)
//
#include <hip/hip_runtime.h>

// Emphasis (y[n] = x[n] - 0.85*x[n-1] via STFT-LFilter), collapsed closed form:
//   interior: y[i] = x[i] + cB[i%256]*x[i-1]
//   tail (last 256/row): y[i] = cAt*x[i] + cBt*x[i-1]   (1e-8 wsum clamp fires at m=255)
// w[n] = sin^2(pi*n/512) (periodic Hann); rows independent; x[-1] = 0.
//
// Structure: grid 2048x256, float4/thread => grid stride == T_ROW exactly, so each
// thread owns ONE in-row offset across all 8 rows: coefficients are loop-invariant
// registers; x[i-1] comes from __shfl_up (lane 0: rare cached scalar load).
// NOTE: no nontemporal hints — nt stores bypass L2 and race with the harness's
// L2-resident 0xAA re-poison (round-4 post-timing divergence).

constexpr int T_ROW = 1 << 21;     // 2097152 samples per (B,C) row
constexpr int N_ROWS = 8;
constexpr float ALPHA_C = 0.85f;

typedef float f32x4 __attribute__((ext_vector_type(4)));

__global__ __launch_bounds__(256) void emphasis_kernel(
    const float* __restrict__ x, float* __restrict__ y)
{
    const int tid = blockIdx.x * 256 + threadIdx.x;   // 0 .. 524287
    const long long off = (long long)tid * 4;         // element offset within a row
    const int m = (int)(off & 255);

    // Per-thread loop-invariant coefficients: y[j] = cA[j]*x[j] + cB[j]*x[j-1]
    float cA[4], cB[4];
    const bool tail = (off >= (long long)(T_ROW - 256));   // wave-uniform
    #pragma unroll
    for (int j = 0; j < 4; ++j) {
        const float fm = (float)(m + j);
        const float s     = sinpif(fm * (1.0f / 512.0f));
        const float c     = cospif(fm * (1.0f / 512.0f));
        const float wm    = s * s;          // w[m]      (exactly 0 at m=0)
        const float wm256 = c * c;          // w[m+256]
        const float s1    = sinpif((fm - 1.0f) * (1.0f / 512.0f));
        const float wm1   = s1 * s1;        // w[m-1]    (m=0: killed by wm=0)
        const float s255  = sinpif((fm + 255.0f) * (1.0f / 512.0f));
        const float wm255 = s255 * s255;    // w[m+255]
        if (tail) {                          // single covering frame + wsum clamp
            const float wn2 = wm256 * wm256;
            const float d   = fmaxf(wn2, 1e-8f);
            cA[j] = wn2 / d;
            cB[j] = (-ALPHA_C * wm256 * wm255) / d;
        } else {                             // two frames; denom in [0.5,1]
            const float A = fmaxf(wm * wm + wm256 * wm256, 1e-8f);
            cA[j] = 1.0f;
            cB[j] = (-ALPHA_C * (wm * wm1 + wm256 * wm255)) / A;
        }
    }

    const int lane = threadIdx.x & 63;
    const float* xr = x + off;
    float* yr = y + off;
    #pragma unroll
    for (int b = 0; b < N_ROWS; ++b) {
        const long long ro = (long long)b * T_ROW;
        const f32x4 xv = *reinterpret_cast<const f32x4*>(xr + ro);
        float xm1 = __shfl_up(xv.w, 1);                 // lanes 1..63: neighbor's x[i-1]
        if (lane == 0) xm1 = (off == 0) ? 0.0f : xr[ro - 1];  // cached scalar load
        f32x4 o;
        o.x = cA[0] * xv.x + cB[0] * xm1;
        o.y = cA[1] * xv.y + cB[1] * xv.x;
        o.z = cA[2] * xv.z + cB[2] * xv.y;
        o.w = cA[3] * xv.w + cB[3] * xv.z;
        *reinterpret_cast<f32x4*>(yr + ro) = o;
    }
}

extern "C" void kernel_launch(void* const* d_in, const int* in_sizes, int n_in,
                              void* d_out, int out_size, void* d_ws, size_t ws_size,
                              hipStream_t stream) {
    const float* x = (const float*)d_in[0];
    float* y = (float*)d_out;
    // out_size = 8 * 2097152; one thread per 4 elements of one row across all rows
    const int nthreads = T_ROW / 4;          // 524288
    const int block = 256;
    const int grid = nthreads / block;       // 2048
    emphasis_kernel<<<grid, block, 0, stream>>>(x, y);
}